// Round 16
// baseline (383.143 us; speedup 1.0000x reference)
//
#include <hip/hip_runtime.h>
#include <hip/hip_bf16.h>
#include <cstdint>

// Problem constants: B,T,E,C,I_E,O = 4,2048,8,512,512,4096
constexpr int NB = 4;
constexpr int NT = 2048;
constexpr int NE = 8;
constexpr int NC = 512;
constexpr int NI = 512;
constexpr int NO = 4096;
constexpr int NEC = NE * NC;   // 4096
constexpr int NEI = NE * NI;   // 4096 (restructured stage-2 K)

typedef __attribute__((ext_vector_type(8))) short short8;
typedef __attribute__((ext_vector_type(8))) unsigned short ushort8;
typedef __attribute__((ext_vector_type(4))) float f32x4;
typedef __attribute__((ext_vector_type(16))) float f32x16;

__device__ __forceinline__ unsigned short f2bf(float f) {
  unsigned int u = __builtin_bit_cast(unsigned int, f);
  u += 0x7FFFu + ((u >> 16) & 1u);
  return (unsigned short)(u >> 16);
}

__device__ __forceinline__ ushort8 cvt8(float4 a, float4 b) {
  ushort8 v;
  v[0] = f2bf(a.x); v[1] = f2bf(a.y); v[2] = f2bf(a.z); v[3] = f2bf(a.w);
  v[4] = f2bf(b.x); v[5] = f2bf(b.y); v[6] = f2bf(b.z); v[7] = f2bf(b.w);
  return v;
}

// swizzle for the fallback 128x32 tiles
__device__ __forceinline__ int lds_byte(int row, int kbyte) {
  return (row * 64 + kbyte) ^ ((row & 6) << 3);
}

__device__ __forceinline__ void gload_lds16(const void* g, void* lds) {
  __builtin_amdgcn_global_load_lds(
      (const __attribute__((address_space(1))) unsigned int*)g,
      (__attribute__((address_space(3))) unsigned int*)lds, 16, 0, 0);
}

// ===========================================================================
// Conversion / permutation passes
// ===========================================================================

// comb f32 [B,T,E,C] -> cbp bf16 (same layout) + S[b*T+t] = row sum (f32)
__global__ __launch_bounds__(256) void k_cvt_comb(
    const float* __restrict__ comb, unsigned short* __restrict__ cbp,
    float* __restrict__ S) {
  const int row = blockIdx.x;  // 8192 rows of 4096
  const float* src = comb + (size_t)row * NEC;
  unsigned short* dst = cbp + (size_t)row * NEC;
  const int tid = threadIdx.x;
  float sum = 0.f;
#pragma unroll
  for (int it = 0; it < 2; ++it) {
    const int i8 = tid + it * 256;
    const float4* s = (const float4*)(src + i8 * 8);
    float4 a = s[0], b4 = s[1];
    *(ushort8*)(dst + i8 * 8) = cvt8(a, b4);
    sum += a.x + a.y + a.z + a.w + b4.x + b4.y + b4.z + b4.w;
  }
  for (int off = 32; off > 0; off >>= 1) sum += __shfl_down(sum, off);
  __shared__ float ws4[4];
  if ((tid & 63) == 0) ws4[tid >> 6] = sum;
  __syncthreads();
  if (tid == 0) S[row] = ws4[0] + ws4[1] + ws4[2] + ws4[3];
}

// x f32 [B,E,C,I] -> xT bf16 [B,E,I,C]  (64x64 LDS-tiled transpose)
__global__ __launch_bounds__(256) void k_cvtT_x(
    const float* __restrict__ x, unsigned short* __restrict__ xT) {
  const int be = blockIdx.x >> 6;    // 32
  const int tile = blockIdx.x & 63;  // 8x8 tiles
  const int c0 = (tile >> 3) * 64, i0 = (tile & 7) * 64;
  const float* src = x + (size_t)be * NC * NI;
  unsigned short* dst = xT + (size_t)be * NI * NC;
  __shared__ unsigned short tl[64][65];
  const int lr = threadIdx.x >> 6, lc = threadIdx.x & 63;
#pragma unroll
  for (int s = 0; s < 16; ++s) {
    const int c = s * 4 + lr;
    tl[c][lc] = f2bf(src[(size_t)(c0 + c) * NI + i0 + lc]);
  }
  __syncthreads();
#pragma unroll
  for (int s = 0; s < 16; ++s) {
    const int i = s * 4 + lr;
    dst[(size_t)(i0 + i) * NC + c0 + lc] = tl[lc][i];
  }
}

// W f32 [E,O,I] -> Wt bf16 [O,E,I]  (coalesced both sides; i innermost)
__global__ __launch_bounds__(256) void k_cvtT_W(
    const float* __restrict__ W, unsigned short* __restrict__ Wt) {
  const size_t n8 = (size_t)NE * NO * NI / 8;  // 2,097,152
  size_t idx = (size_t)blockIdx.x * 256 + threadIdx.x;
  const size_t stride = (size_t)gridDim.x * 256;
  for (; idx < n8; idx += stride) {
    const int i8 = (int)(idx & (NI / 8 - 1));
    const size_t eo = idx >> 6;          // e*O + o
    const int e = (int)(eo >> 12);
    const int o = (int)(eo & 4095);
    const float4* s = (const float4*)(W + eo * NI + i8 * 8);
    float4 a = s[0], b4 = s[1];
    *(ushort8*)(Wt + ((size_t)o * NE + e) * NI + i8 * 8) = cvt8(a, b4);
  }
}

// ===========================================================================
// 256x256 4-merged-phase READ-AHEAD core — 32x32x16 MFMA variant.
// Schedule = r13's verified best (235.1 us) verbatim; only the fragment
// shape changes: per phase 8x mfma_f32_32x32x16_bf16 replaces 16x
// 16x16x32 (same FLOPs, 2382 vs 2075 TF ceiling, half the instructions).
// Read counts are IDENTICAL (LDA4 = 4x16B: 2 M-frags x 2 k-steps;
// LDB4 = 4x16B: 2 N-frags x 2 k-steps) so every LG4/LG8/VM4/BAR proof
// from r13 carries over unchanged.
// A-frag mapping: row = lane&31, k = 8*(lane>>5)+[0..7] (analog of the
// verified 16x16 mapping). C/D: col=lane&31, row=(reg&3)+8*(reg>>2)+
// 4*(lane>>5) [m74/m101-verified].
// Bank pattern per 16-lane HW pass: rows span 16 consecutive values,
// chunk = (s*2+kb) ^ ((row>>1)&3) -> 8 slots x2 -> 2-way free (same as
// the PMC-verified-0 r9 design). Store-side involution unchanged.
// ===========================================================================
template <int NKT>
__device__ __forceinline__ void gemm8_core(
    const unsigned short* __restrict__ Ag,
    const unsigned short* __restrict__ Bg,
    const int ldkA, const int ldkB, unsigned short* lds, f32x16 (&acc)[8]) {
  const int tid = threadIdx.x, lane = tid & 63, wv = tid >> 6;
  const int wr = wv >> 2, wc = wv & 3;
  const int fr32 = lane & 31;           // frag row/col within 32
  const int kb = lane >> 5;             // k-group (0/1)
  // physical chunk byte offsets for k-step s=0 / s=1 (lane constants)
  const int pc0 = ((kb) ^ ((lane >> 1) & 3)) << 4;
  const int pc1 = pc0 ^ 32;             // chunk s=1 = chunk s=0 ^ 2

  const int scg = (lane & 3) ^ ((lane >> 3) & 3);
  const size_t srow0A = (size_t)(wv * 16 + (lane >> 2)) * ldkA + scg * 8;
  const size_t srow0B = (size_t)(wv * 16 + (lane >> 2)) * ldkB + scg * 8;
  const size_t srstA = (size_t)128 * ldkA;
  const size_t srstB = (size_t)128 * ldkB;
  const int sdst0 = wv * 512;

#define ASLOT(D, KH) ((D) * 16384 + (KH) * 8192)
#define BSLOT(D, KH) (32768 + (D) * 16384 + (KH) * 8192)
#define STG(PTR, SR0, SRST, SLOT, KT, KH)                                  \
  {                                                                        \
    const unsigned short* _g = (PTR) + (SR0) + (size_t)(KT) * 64 + (KH) * 32; \
    gload_lds16(_g, lds + (SLOT) + sdst0);                                 \
    gload_lds16(_g + (SRST), lds + (SLOT) + 4096 + sdst0);                 \
  }
#define RD8P(SLOT, R, PC) \
  (*(const short8*)((const char*)lds + (SLOT) * 2 + (R) * 64 + (PC)))

  short8 afA[4], afB[4], bfA[4], bfB[4];

  // A frags for (D,KH,MH): [m*2+s] = rows MH*64+m*32+fr32, k-step s
#define LDA4(SET, D, KH, MH)                                         \
  _Pragma("unroll") for (int m = 0; m < 2; ++m) {                    \
    const int r_ = wr * 128 + (MH) * 64 + m * 32 + fr32;             \
    SET[m * 2 + 0] = RD8P(ASLOT(D, KH), r_, pc0);                    \
    SET[m * 2 + 1] = RD8P(ASLOT(D, KH), r_, pc1);                    \
  }
  // B frags for (D,KH): [n*2+s] = cols wc*64+n*32+fr32, k-step s
#define LDB4(SET, D, KH)                                             \
  _Pragma("unroll") for (int n = 0; n < 2; ++n) {                    \
    const int r_ = wc * 64 + n * 32 + fr32;                          \
    SET[n * 2 + 0] = RD8P(BSLOT(D, KH), r_, pc0);                    \
    SET[n * 2 + 1] = RD8P(BSLOT(D, KH), r_, pc1);                    \
  }
#define MFMAQ(ASET, BSET, MH)                                        \
  __builtin_amdgcn_s_setprio(1);                                     \
  _Pragma("unroll") for (int m = 0; m < 2; ++m)                      \
  _Pragma("unroll") for (int n = 0; n < 2; ++n) {                    \
    f32x16 c_ = acc[(MH) * 4 + m * 2 + n];                           \
    c_ = __builtin_amdgcn_mfma_f32_32x32x16_bf16(                    \
        ASET[m * 2 + 0], BSET[n * 2 + 0], c_, 0, 0, 0);              \
    c_ = __builtin_amdgcn_mfma_f32_32x32x16_bf16(                    \
        ASET[m * 2 + 1], BSET[n * 2 + 1], c_, 0, 0, 0);              \
    acc[(MH) * 4 + m * 2 + n] = c_;                                  \
  }                                                                  \
  __builtin_amdgcn_s_setprio(0);
#define LG4()                                          \
  asm volatile("s_waitcnt lgkmcnt(4)" ::: "memory");   \
  __builtin_amdgcn_sched_barrier(0)
#define LG8()                                          \
  asm volatile("s_waitcnt lgkmcnt(8)" ::: "memory");   \
  __builtin_amdgcn_sched_barrier(0)
#define VM4() asm volatile("s_waitcnt vmcnt(4)" ::: "memory")
#define BAR() __builtin_amdgcn_s_barrier()

  // prologue (r13): stage A00,B00,A01,B01,A10,B10; vmcnt(4); BAR; preload.
  STG(Ag, srow0A, srstA, ASLOT(0, 0), 0, 0);
  STG(Bg, srow0B, srstB, BSLOT(0, 0), 0, 0);
  STG(Ag, srow0A, srstA, ASLOT(0, 1), 0, 1);
  STG(Bg, srow0B, srstB, BSLOT(0, 1), 0, 1);
  STG(Ag, srow0A, srstA, ASLOT(1, 0), 1, 0);
  STG(Bg, srow0B, srstB, BSLOT(1, 0), 1, 0);
  asm volatile("s_waitcnt vmcnt(4)" ::: "memory");
  BAR();
  LDA4(afA, 0, 0, 0); LDB4(bfA, 0, 0);

  for (int it = 0; it < NKT / 2; ++it) {
    const int k1 = (2 * it + 1) & (NKT - 1);
    const int k2 = (2 * it + 2) & (NKT - 1);
    const int k3 = (2 * it + 3) & (NKT - 1);
    // M1: stages A11,B11<-k1; VM4 proves A10,B10
    STG(Ag, srow0A, srstA, ASLOT(1, 1), k1, 1);
    LDA4(afB, 0, 0, 1);
    LG4();
    MFMAQ(afA, bfA, 0);
    STG(Bg, srow0B, srstB, BSLOT(1, 1), k1, 1);
    VM4();
    LDA4(afA, 0, 1, 0); LDB4(bfB, 0, 1);
    LG8();
    MFMAQ(afB, bfA, 1);
    BAR();
    // M2: stages A00,B00<-k2; VM4 proves A11,B11
    STG(Ag, srow0A, srstA, ASLOT(0, 0), k2, 0);
    LDA4(afB, 0, 1, 1);
    LG4();
    MFMAQ(afA, bfB, 0);
    STG(Bg, srow0B, srstB, BSLOT(0, 0), k2, 0);
    VM4();
    LDA4(afA, 1, 0, 0); LDB4(bfA, 1, 0);
    LG8();
    MFMAQ(afB, bfB, 1);
    BAR();
    // M3: stages A01,B01<-k2; VM4 proves A00,B00
    STG(Ag, srow0A, srstA, ASLOT(0, 1), k2, 1);
    LDA4(afB, 1, 0, 1);
    LG4();
    MFMAQ(afA, bfA, 0);
    STG(Bg, srow0B, srstB, BSLOT(0, 1), k2, 1);
    VM4();
    LDA4(afA, 1, 1, 0); LDB4(bfB, 1, 1);
    LG8();
    MFMAQ(afB, bfA, 1);
    BAR();
    // M4: stages A10,B10<-k3; VM4 proves A01,B01
    STG(Ag, srow0A, srstA, ASLOT(1, 0), k3, 0);
    LDA4(afB, 1, 1, 1);
    LG4();
    MFMAQ(afA, bfB, 0);
    STG(Bg, srow0B, srstB, BSLOT(1, 0), k3, 0);
    VM4();
    LDA4(afA, 0, 0, 0); LDB4(bfA, 0, 0);
    LG8();
    MFMAQ(afB, bfB, 1);
    BAR();
  }
  asm volatile("s_waitcnt vmcnt(0) lgkmcnt(0)" ::: "memory");
#undef ASLOT
#undef BSLOT
#undef STG
#undef RD8P
#undef LDA4
#undef LDB4
#undef MFMAQ
#undef LG4
#undef LG8
#undef VM4
#undef BAR
}

// Stage 1': Y[b,t,e*512+i] = sum_c comb[b,t,e,c] * xT[b,e,i,c]   (bf16 out)
__global__ __launch_bounds__(512, 2) void k_gemm1q(
    const unsigned short* __restrict__ cbp, const unsigned short* __restrict__ xT,
    unsigned short* __restrict__ Y) {
  const int bid = (blockIdx.x & 7) * 64 + (blockIdx.x >> 3);  // 512%8==0
  const int be = bid >> 4, tile = bid & 15;
  const int b = be >> 3, e = be & 7;
  const int bm = tile >> 1, bn = tile & 1;

  const int tid = threadIdx.x, lane = tid & 63, wv = tid >> 6;
  const int wr = wv >> 2, wc = wv & 3;
  const int col = lane & 31, hi = lane >> 5;

  const unsigned short* Ag =
      cbp + (size_t)b * NT * NEC + (size_t)(bm * 256) * NEC + e * NC;
  const unsigned short* Bg =
      xT + (size_t)be * NI * NC + (size_t)(bn * 256) * NC;

  __shared__ __align__(16) unsigned short lds[65536];

  f32x16 acc[8];
#pragma unroll
  for (int f = 0; f < 8; ++f) acc[f] = (f32x16)0.f;

  gemm8_core<NC / 64>(Ag, Bg, NEC, NC, lds, acc);

  const int t0 = bm * 256 + wr * 128;
  const int i0c = bn * 256 + wc * 64;
#pragma unroll
  for (int f = 0; f < 8; ++f) {
    const int MH = f >> 2, mm = (f >> 1) & 1, nn = f & 1;
    const int ic = i0c + nn * 32 + col;
#pragma unroll
    for (int q = 0; q < 4; ++q) {
#pragma unroll
      for (int j = 0; j < 4; ++j) {
        const int t = t0 + MH * 64 + mm * 32 + q * 8 + j + hi * 4;
        Y[((size_t)b * NT + t) * NEI + e * NI + ic] = f2bf(acc[f][q * 4 + j]);
      }
    }
  }
}

// Stage 2': out[b,t,o] = sum_{ei} Y[b,t,ei] * Wt[o,ei] + bias[o]*S[b,t]
__global__ __launch_bounds__(512, 2) void k_gemm2q(
    const unsigned short* __restrict__ Y, const unsigned short* __restrict__ Wt,
    const float* __restrict__ bias, const float* __restrict__ S,
    float* __restrict__ out) {
  const int bid = (blockIdx.x & 7) * 64 + (blockIdx.x >> 3);  // 512%8==0
  const int b  = bid >> 7;
  const int bm = (bid >> 4) & 7;
  const int bn = bid & 15;

  const int tid = threadIdx.x, lane = tid & 63, wv = tid >> 6;
  const int wr = wv >> 2, wc = wv & 3;
  const int col = lane & 31, hi = lane >> 5;

  const unsigned short* Ag = Y + (size_t)b * NT * NEI + (size_t)(bm * 256) * NEI;
  const unsigned short* Bg = Wt + (size_t)(bn * 256) * NEI;

  __shared__ __align__(16) unsigned short lds[65536];

  f32x16 acc[8];
#pragma unroll
  for (int f = 0; f < 8; ++f) acc[f] = (f32x16)0.f;

  gemm8_core<NEI / 64>(Ag, Bg, NEI, NEI, lds, acc);

  const int t0 = bm * 256 + wr * 128;
  const int o0 = bn * 256 + wc * 64;
  float bv[2];
#pragma unroll
  for (int n = 0; n < 2; ++n) bv[n] = bias[o0 + n * 32 + col];
#pragma unroll
  for (int f = 0; f < 8; ++f) {
    const int MH = f >> 2, mm = (f >> 1) & 1, nn = f & 1;
#pragma unroll
    for (int q = 0; q < 4; ++q) {
#pragma unroll
      for (int j = 0; j < 4; ++j) {
        const int t = t0 + MH * 64 + mm * 32 + q * 8 + j + hi * 4;
        const float sv = S[b * NT + t];
        out[((size_t)b * NT + t) * NO + o0 + nn * 32 + col] =
            acc[f][q * 4 + j] + bv[nn] * sv;
      }
    }
  }
}

// ===========================================================================
// FALLBACK (round-4 verified) — used when ws_size < ~185 MB
// ===========================================================================
__global__ __launch_bounds__(256, 2) void k_gemm1(
    const float* __restrict__ x, const float* __restrict__ W,
    const float* __restrict__ bias, unsigned short* __restrict__ eoT) {
  const int tile = blockIdx.x;
  const int e = blockIdx.y, b = blockIdx.z;
  const int bm = tile >> 2, bn = tile & 3;
  const int tid = threadIdx.x, lane = tid & 63, wv = tid >> 6;
  const int wr = wv >> 1, wc = wv & 1;

  const float* Ag = W + (size_t)e * NO * NI + (size_t)(bm * 128) * NI;
  const float* Bg = x + ((size_t)b * NE + e) * NC * NI + (size_t)(bn * 128) * NI;

  __shared__ __align__(16) unsigned short As[128 * 32];
  __shared__ __align__(16) unsigned short Bs[128 * 32];

  f32x4 acc[4][4];
#pragma unroll
  for (int m = 0; m < 4; ++m)
#pragma unroll
    for (int n = 0; n < 4; ++n) acc[m][n] = (f32x4)0.f;

  for (int k0 = 0; k0 < NI; k0 += 32) {
    __syncthreads();
#pragma unroll
    for (int s = 0; s < 2; ++s) {
      const int q = tid + s * 256;
      const int row = q >> 2, kc = (q & 3) * 8;
      const float* ga = Ag + (size_t)row * NI + k0 + kc;
      float4 a0 = *(const float4*)ga;
      float4 a1 = *(const float4*)(ga + 4);
      *(ushort8*)((char*)As + lds_byte(row, kc * 2)) = cvt8(a0, a1);
      const float* gb = Bg + (size_t)row * NI + k0 + kc;
      float4 b0 = *(const float4*)gb;
      float4 b1 = *(const float4*)(gb + 4);
      *(ushort8*)((char*)Bs + lds_byte(row, kc * 2)) = cvt8(b0, b1);
    }
    __syncthreads();

    const int kb = (lane >> 4) * 16;
    short8 af[4], bfv[4];
#pragma unroll
    for (int m = 0; m < 4; ++m) {
      const int r = wr * 64 + m * 16 + (lane & 15);
      af[m] = *(const short8*)((const char*)As + lds_byte(r, kb));
    }
#pragma unroll
    for (int n = 0; n < 4; ++n) {
      const int r = wc * 64 + n * 16 + (lane & 15);
      bfv[n] = *(const short8*)((const char*)Bs + lds_byte(r, kb));
    }
#pragma unroll
    for (int m = 0; m < 4; ++m)
#pragma unroll
      for (int n = 0; n < 4; ++n)
        acc[m][n] = __builtin_amdgcn_mfma_f32_16x16x32_bf16(
            af[m], bfv[n], acc[m][n], 0, 0, 0);
  }

  const int o0 = bm * 128 + wr * 64;
  const int c0 = bn * 128 + wc * 64;
#pragma unroll
  for (int m = 0; m < 4; ++m) {
#pragma unroll
    for (int j = 0; j < 4; ++j) {
      const int o = o0 + m * 16 + (lane >> 4) * 4 + j;
      const float bvv = bias[o];
      const size_t base = (((size_t)b * NO + o) * NE + e) * NC + c0;
#pragma unroll
      for (int n = 0; n < 4; ++n)
        eoT[base + n * 16 + (lane & 15)] = f2bf(acc[m][n][j] + bvv);
    }
  }
}

__global__ __launch_bounds__(256, 2) void k_gemm2(
    const float* __restrict__ comb, const unsigned short* __restrict__ eoT,
    float* __restrict__ out) {
  const int b = blockIdx.y;
  const int bm = blockIdx.x >> 5;
  const int bn = blockIdx.x & 31;
  const int tid = threadIdx.x, lane = tid & 63, wv = tid >> 6;
  const int wr = wv >> 1, wc = wv & 1;

  const float* Ag = comb + (size_t)b * NT * NEC + (size_t)(bm * 128) * NEC;
  const unsigned short* Bg = eoT + (size_t)b * NO * NEC + (size_t)(bn * 128) * NEC;

  __shared__ __align__(16) unsigned short As[128 * 32];
  __shared__ __align__(16) unsigned short Bs[128 * 32];

  f32x4 acc[4][4];
#pragma unroll
  for (int m = 0; m < 4; ++m)
#pragma unroll
    for (int n = 0; n < 4; ++n) acc[m][n] = (f32x4)0.f;

  for (int k0 = 0; k0 < NEC; k0 += 32) {
    __syncthreads();
#pragma unroll
    for (int s = 0; s < 2; ++s) {
      const int q = tid + s * 256;
      const int row = q >> 2, kc = (q & 3) * 8;
      const float* ga = Ag + (size_t)row * NEC + k0 + kc;
      float4 a0 = *(const float4*)ga;
      float4 a1 = *(const float4*)(ga + 4);
      *(ushort8*)((char*)As + lds_byte(row, kc * 2)) = cvt8(a0, a1);
      ushort8 bvv = *(const ushort8*)(Bg + (size_t)row * NEC + k0 + kc);
      *(ushort8*)((char*)Bs + lds_byte(row, kc * 2)) = bvv;
    }
    __syncthreads();

    const int kb = (lane >> 4) * 16;
    short8 af[4], bfv[4];
#pragma unroll
    for (int m = 0; m < 4; ++m) {
      const int r = wr * 64 + m * 16 + (lane & 15);
      af[m] = *(const short8*)((const char*)As + lds_byte(r, kb));
    }
#pragma unroll
    for (int n = 0; n < 4; ++n) {
      const int r = wc * 64 + n * 16 + (lane & 15);
      bfv[n] = *(const short8*)((const char*)Bs + lds_byte(r, kb));
    }
#pragma unroll
    for (int m = 0; m < 4; ++m)
#pragma unroll
      for (int n = 0; n < 4; ++n)
        acc[m][n] = __builtin_amdgcn_mfma_f32_16x16x32_bf16(
            af[m], bfv[n], acc[m][n], 0, 0, 0);
  }

  const int t0 = bm * 128 + wr * 64;
  const int o0 = bn * 128 + wc * 64;
#pragma unroll
  for (int m = 0; m < 4; ++m) {
#pragma unroll
    for (int j = 0; j < 4; ++j) {
      const int t = t0 + m * 16 + (lane >> 4) * 4 + j;
      float* op = out + ((size_t)b * NT + t) * NO + o0;
#pragma unroll
      for (int n = 0; n < 4; ++n) op[n * 16 + (lane & 15)] = acc[m][n][j];
    }
  }
}

extern "C" void kernel_launch(void* const* d_in, const int* in_sizes, int n_in,
                              void* d_out, int out_size, void* d_ws, size_t ws_size,
                              hipStream_t stream) {
  const float* x    = (const float*)d_in[0];  // [B,E,C,I]
  const float* comb = (const float*)d_in[1];  // [B,T,E,C]
  const float* W    = (const float*)d_in[2];  // [E,O,I]
  const float* bias = (const float*)d_in[3];  // [O]
  float* out = (float*)d_out;                 // [B,T,O]

  // Restructured workspace: Y | cbp | xT | Wt | S
  const size_t Y_ELEMS  = (size_t)NB * NT * NEI;  // 33,554,432
  const size_t C_ELEMS  = (size_t)NB * NT * NEC;  // 33,554,432
  const size_t XT_ELEMS = (size_t)NB * NE * NI * NC;  // 8,388,608
  const size_t WT_ELEMS = (size_t)NO * NE * NI;   // 16,777,216
  const size_t need =
      (Y_ELEMS + C_ELEMS + XT_ELEMS + WT_ELEMS) * 2 + (size_t)NB * NT * 4;

  if (ws_size >= need) {
    unsigned short* Yp  = (unsigned short*)d_ws;
    unsigned short* cbp = Yp + Y_ELEMS;
    unsigned short* xT  = cbp + C_ELEMS;
    unsigned short* Wt  = xT + XT_ELEMS;
    float* S = (float*)(Wt + WT_ELEMS);

    k_cvtT_x<<<2048, 256, 0, stream>>>(x, xT);
    k_cvt_comb<<<NB * NT, 256, 0, stream>>>(comb, cbp, S);
    k_gemm1q<<<512, 512, 0, stream>>>(cbp, xT, Yp);
    k_cvtT_W<<<2048, 256, 0, stream>>>(W, Wt);
    k_gemm2q<<<512, 512, 0, stream>>>(Yp, Wt, bias, S, out);
  } else {
    // Fallback: round-4 verified reg-staged kernels (needs only 134MB)
    unsigned short* eoT = (unsigned short*)d_ws;
    k_gemm1<<<dim3(128, NE, NB), 256, 0, stream>>>(x, W, bias, eoT);
    k_gemm2<<<dim3(512, NB), 256, 0, stream>>>(comb, eoT, out);
  }
}

// Round 17
// 351.808 us; speedup vs baseline: 1.0891x; 1.0891x over previous
//
#include <hip/hip_runtime.h>
#include <hip/hip_bf16.h>
#include <cstdint>

// Problem constants: B,T,E,C,I_E,O = 4,2048,8,512,512,4096
constexpr int NB = 4;
constexpr int NT = 2048;
constexpr int NE = 8;
constexpr int NC = 512;
constexpr int NI = 512;
constexpr int NO = 4096;
constexpr int NEC = NE * NC;   // 4096
constexpr int NEI = NE * NI;   // 4096 (restructured stage-2 K)

typedef __attribute__((ext_vector_type(8))) short short8;
typedef __attribute__((ext_vector_type(8))) unsigned short ushort8;
typedef __attribute__((ext_vector_type(4))) float f32x4;

__device__ __forceinline__ unsigned short f2bf(float f) {
  unsigned int u = __builtin_bit_cast(unsigned int, f);
  u += 0x7FFFu + ((u >> 16) & 1u);
  return (unsigned short)(u >> 16);
}

__device__ __forceinline__ ushort8 cvt8(float4 a, float4 b) {
  ushort8 v;
  v[0] = f2bf(a.x); v[1] = f2bf(a.y); v[2] = f2bf(a.z); v[3] = f2bf(a.w);
  v[4] = f2bf(b.x); v[5] = f2bf(b.y); v[6] = f2bf(b.z); v[7] = f2bf(b.w);
  return v;
}

// swizzle for the fallback 128x32 tiles
__device__ __forceinline__ int lds_byte(int row, int kbyte) {
  return (row * 64 + kbyte) ^ ((row & 6) << 3);
}

__device__ __forceinline__ void gload_lds16(const void* g, void* lds) {
  __builtin_amdgcn_global_load_lds(
      (const __attribute__((address_space(1))) unsigned int*)g,
      (__attribute__((address_space(3))) unsigned int*)lds, 16, 0, 0);
}

// ===========================================================================
// Conversion / permutation passes
// ===========================================================================

// comb f32 [B,T,E,C] -> cbp bf16 (same layout) + S[b*T+t] = row sum (f32)
__global__ __launch_bounds__(256) void k_cvt_comb(
    const float* __restrict__ comb, unsigned short* __restrict__ cbp,
    float* __restrict__ S) {
  const int row = blockIdx.x;  // 8192 rows of 4096
  const float* src = comb + (size_t)row * NEC;
  unsigned short* dst = cbp + (size_t)row * NEC;
  const int tid = threadIdx.x;
  float sum = 0.f;
#pragma unroll
  for (int it = 0; it < 2; ++it) {
    const int i8 = tid + it * 256;
    const float4* s = (const float4*)(src + i8 * 8);
    float4 a = s[0], b4 = s[1];
    *(ushort8*)(dst + i8 * 8) = cvt8(a, b4);
    sum += a.x + a.y + a.z + a.w + b4.x + b4.y + b4.z + b4.w;
  }
  for (int off = 32; off > 0; off >>= 1) sum += __shfl_down(sum, off);
  __shared__ float ws4[4];
  if ((tid & 63) == 0) ws4[tid >> 6] = sum;
  __syncthreads();
  if (tid == 0) S[row] = ws4[0] + ws4[1] + ws4[2] + ws4[3];
}

// x f32 [B,E,C,I] -> xT bf16 [B,E,I,C]  (64x64 LDS-tiled transpose)
__global__ __launch_bounds__(256) void k_cvtT_x(
    const float* __restrict__ x, unsigned short* __restrict__ xT) {
  const int be = blockIdx.x >> 6;    // 32
  const int tile = blockIdx.x & 63;  // 8x8 tiles
  const int c0 = (tile >> 3) * 64, i0 = (tile & 7) * 64;
  const float* src = x + (size_t)be * NC * NI;
  unsigned short* dst = xT + (size_t)be * NI * NC;
  __shared__ unsigned short tl[64][65];
  const int lr = threadIdx.x >> 6, lc = threadIdx.x & 63;
#pragma unroll
  for (int s = 0; s < 16; ++s) {
    const int c = s * 4 + lr;
    tl[c][lc] = f2bf(src[(size_t)(c0 + c) * NI + i0 + lc]);
  }
  __syncthreads();
#pragma unroll
  for (int s = 0; s < 16; ++s) {
    const int i = s * 4 + lr;
    dst[(size_t)(i0 + i) * NC + c0 + lc] = tl[lc][i];
  }
}

// W f32 [E,O,I] -> Wt bf16 [O,E,I]  (coalesced both sides; i innermost)
__global__ __launch_bounds__(256) void k_cvtT_W(
    const float* __restrict__ W, unsigned short* __restrict__ Wt) {
  const size_t n8 = (size_t)NE * NO * NI / 8;  // 2,097,152
  size_t idx = (size_t)blockIdx.x * 256 + threadIdx.x;
  const size_t stride = (size_t)gridDim.x * 256;
  for (; idx < n8; idx += stride) {
    const int i8 = (int)(idx & (NI / 8 - 1));
    const size_t eo = idx >> 6;          // e*O + o
    const int e = (int)(eo >> 12);
    const int o = (int)(eo & 4095);
    const float4* s = (const float4*)(W + eo * NI + i8 * 8);
    float4 a = s[0], b4 = s[1];
    *(ushort8*)(Wt + ((size_t)o * NE + e) * NI + i8 * 8) = cvt8(a, b4);
  }
}

// ===========================================================================
// 256x256 4-merged-phase READ-AHEAD pipeline core (r13, best verified:
// gemm2q 235.1 us / MfmaUtil 54 / bank-conflicts 0).
// Per merged phase: STG; rd1->alt regset; LG4; MFMA(m0); STG; VM4;
// rd2; LG8; MFMA(m1); BAR. Stage schedule: M1 A11,B11<-k1; M2 A00,B00<-k2;
// M3 A01,B01<-k2; M4 A10,B10<-k3. VM4 proves the previous phase's pair.
// Bank pattern (PMC-verified 0): read chunk = g16 ^ ((fr>>1)&3); source
// chunk pre-swizzled (lane&3)^((lane>>3)&3).
// ===========================================================================
template <int NKT>
__device__ __forceinline__ void gemm8_core(
    const unsigned short* __restrict__ Ag,
    const unsigned short* __restrict__ Bg,
    const int ldkA, const int ldkB, unsigned short* lds, f32x4 (&acc)[8][4]) {
  const int tid = threadIdx.x, lane = tid & 63, wv = tid >> 6;
  const int wr = wv >> 2, wc = wv & 3;
  const int g16 = lane >> 4;
  const int fr  = lane & 15;
  const int pc  = (g16 ^ ((fr >> 1) & 3)) << 4;

  const int scg = (lane & 3) ^ ((lane >> 3) & 3);
  const size_t srow0A = (size_t)(wv * 16 + (lane >> 2)) * ldkA + scg * 8;
  const size_t srow0B = (size_t)(wv * 16 + (lane >> 2)) * ldkB + scg * 8;
  const size_t srstA = (size_t)128 * ldkA;
  const size_t srstB = (size_t)128 * ldkB;
  const int sdst0 = wv * 512;

#define ASLOT(D, KH) ((D) * 16384 + (KH) * 8192)
#define BSLOT(D, KH) (32768 + (D) * 16384 + (KH) * 8192)
#define STG(PTR, SR0, SRST, SLOT, KT, KH)                                  \
  {                                                                        \
    const unsigned short* _g = (PTR) + (SR0) + (size_t)(KT) * 64 + (KH) * 32; \
    gload_lds16(_g, lds + (SLOT) + sdst0);                                 \
    gload_lds16(_g + (SRST), lds + (SLOT) + 4096 + sdst0);                 \
  }
#define RD8(SLOT, R) \
  (*(const short8*)((const char*)lds + (SLOT) * 2 + (R) * 64 + pc))

  short8 afA[4], afB[4], bfA[4], bfB[4];

#define LDA4(SET, D, KH, MH)                                        \
  _Pragma("unroll") for (int m = 0; m < 4; ++m) {                   \
    SET[m] = RD8(ASLOT(D, KH), wr * 128 + (MH) * 64 + m * 16 + fr); \
  }
#define LDB4(SET, D, KH)                                            \
  _Pragma("unroll") for (int n = 0; n < 4; ++n) {                   \
    SET[n] = RD8(BSLOT(D, KH), wc * 64 + n * 16 + fr);              \
  }
#define MFMAQ(ASET, BSET, MH)                                        \
  __builtin_amdgcn_s_setprio(1);                                     \
  _Pragma("unroll") for (int m = 0; m < 4; ++m)                      \
  _Pragma("unroll") for (int n = 0; n < 4; ++n) {                    \
    acc[(MH) * 4 + m][n] = __builtin_amdgcn_mfma_f32_16x16x32_bf16(  \
        ASET[m], BSET[n], acc[(MH) * 4 + m][n], 0, 0, 0);            \
  }                                                                  \
  __builtin_amdgcn_s_setprio(0);
#define LG4()                                          \
  asm volatile("s_waitcnt lgkmcnt(4)" ::: "memory");   \
  __builtin_amdgcn_sched_barrier(0)
#define LG8()                                          \
  asm volatile("s_waitcnt lgkmcnt(8)" ::: "memory");   \
  __builtin_amdgcn_sched_barrier(0)
#define VM4() asm volatile("s_waitcnt vmcnt(4)" ::: "memory")
#define BAR() __builtin_amdgcn_s_barrier()

  // prologue: stage A00,B00,A01,B01,A10,B10; prove first 2 pairs (vmcnt(4));
  // BAR; preload rd(M1-first) = A00,B00 fragments.
  STG(Ag, srow0A, srstA, ASLOT(0, 0), 0, 0);
  STG(Bg, srow0B, srstB, BSLOT(0, 0), 0, 0);
  STG(Ag, srow0A, srstA, ASLOT(0, 1), 0, 1);
  STG(Bg, srow0B, srstB, BSLOT(0, 1), 0, 1);
  STG(Ag, srow0A, srstA, ASLOT(1, 0), 1, 0);
  STG(Bg, srow0B, srstB, BSLOT(1, 0), 1, 0);
  asm volatile("s_waitcnt vmcnt(4)" ::: "memory");
  BAR();
  LDA4(afA, 0, 0, 0); LDB4(bfA, 0, 0);

  for (int it = 0; it < NKT / 2; ++it) {
    const int k1 = (2 * it + 1) & (NKT - 1);
    const int k2 = (2 * it + 2) & (NKT - 1);
    const int k3 = (2 * it + 3) & (NKT - 1);
    // M1: (d0,k0,m0)+(d0,k0,m1); stages A11,B11<-k1; VM4 proves A10,B10
    STG(Ag, srow0A, srstA, ASLOT(1, 1), k1, 1);
    LDA4(afB, 0, 0, 1);
    LG4();
    MFMAQ(afA, bfA, 0);
    STG(Bg, srow0B, srstB, BSLOT(1, 1), k1, 1);
    VM4();
    LDA4(afA, 0, 1, 0); LDB4(bfB, 0, 1);
    LG8();
    MFMAQ(afB, bfA, 1);
    BAR();
    // M2: (d0,k1,m0)+(d0,k1,m1); stages A00,B00<-k2; VM4 proves A11,B11
    STG(Ag, srow0A, srstA, ASLOT(0, 0), k2, 0);
    LDA4(afB, 0, 1, 1);
    LG4();
    MFMAQ(afA, bfB, 0);
    STG(Bg, srow0B, srstB, BSLOT(0, 0), k2, 0);
    VM4();
    LDA4(afA, 1, 0, 0); LDB4(bfA, 1, 0);
    LG8();
    MFMAQ(afB, bfB, 1);
    BAR();
    // M3: (d1,k0,m0)+(d1,k0,m1); stages A01,B01<-k2; VM4 proves A00,B00
    STG(Ag, srow0A, srstA, ASLOT(0, 1), k2, 1);
    LDA4(afB, 1, 0, 1);
    LG4();
    MFMAQ(afA, bfA, 0);
    STG(Bg, srow0B, srstB, BSLOT(0, 1), k2, 1);
    VM4();
    LDA4(afA, 1, 1, 0); LDB4(bfB, 1, 1);
    LG8();
    MFMAQ(afB, bfA, 1);
    BAR();
    // M4: (d1,k1,m0)+(d1,k1,m1); stages A10,B10<-k3; VM4 proves A01,B01
    STG(Ag, srow0A, srstA, ASLOT(1, 0), k3, 0);
    LDA4(afB, 1, 1, 1);
    LG4();
    MFMAQ(afA, bfB, 0);
    STG(Bg, srow0B, srstB, BSLOT(1, 0), k3, 0);
    VM4();
    LDA4(afA, 0, 0, 0); LDB4(bfA, 0, 0);
    LG8();
    MFMAQ(afB, bfB, 1);
    BAR();
  }
  asm volatile("s_waitcnt vmcnt(0) lgkmcnt(0)" ::: "memory");
#undef ASLOT
#undef BSLOT
#undef STG
#undef RD8
#undef LDA4
#undef LDB4
#undef MFMAQ
#undef LG4
#undef LG8
#undef VM4
#undef BAR
}

// Stage 1': Y[b,t,e*512+i] = sum_c comb[b,t,e,c] * xT[b,e,i,c]   (bf16 out)
__global__ __launch_bounds__(512, 2) void k_gemm1q(
    const unsigned short* __restrict__ cbp, const unsigned short* __restrict__ xT,
    unsigned short* __restrict__ Y) {
  const int bid = (blockIdx.x & 7) * 64 + (blockIdx.x >> 3);  // 512%8==0
  const int be = bid >> 4, tile = bid & 15;
  const int b = be >> 3, e = be & 7;
  const int bm = tile >> 1, bn = tile & 1;

  const int tid = threadIdx.x, lane = tid & 63, wv = tid >> 6;
  const int wr = wv >> 2, wc = wv & 3;
  const int g16 = lane >> 4, fr = lane & 15;

  const unsigned short* Ag =
      cbp + (size_t)b * NT * NEC + (size_t)(bm * 256) * NEC + e * NC;
  const unsigned short* Bg =
      xT + (size_t)be * NI * NC + (size_t)(bn * 256) * NC;

  __shared__ __align__(16) unsigned short lds[65536];

  f32x4 acc[8][4];
#pragma unroll
  for (int m = 0; m < 8; ++m)
#pragma unroll
    for (int n = 0; n < 4; ++n) acc[m][n] = (f32x4)0.f;

  gemm8_core<NC / 64>(Ag, Bg, NEC, NC, lds, acc);

  const int t0 = bm * 256 + wr * 128;
  const int i0c = bn * 256 + wc * 64;
#pragma unroll
  for (int ii = 0; ii < 8; ++ii) {
#pragma unroll
    for (int j = 0; j < 4; ++j) {
      const int t = t0 + (ii >> 2) * 64 + (ii & 3) * 16 + g16 * 4 + j;
      unsigned short* yp = Y + ((size_t)b * NT + t) * NEI + e * NI + i0c;
#pragma unroll
      for (int n = 0; n < 4; ++n) yp[n * 16 + fr] = f2bf(acc[ii][n][j]);
    }
  }
}

// Stage 2': out[b,t,o] = sum_{ei} Y[b,t,ei] * Wt[o,ei] + bias[o]*S[b,t]
__global__ __launch_bounds__(512, 2) void k_gemm2q(
    const unsigned short* __restrict__ Y, const unsigned short* __restrict__ Wt,
    const float* __restrict__ bias, const float* __restrict__ S,
    float* __restrict__ out) {
  const int bid = (blockIdx.x & 7) * 64 + (blockIdx.x >> 3);  // 512%8==0
  const int b  = bid >> 7;
  const int bm = (bid >> 4) & 7;
  const int bn = bid & 15;

  const int tid = threadIdx.x, lane = tid & 63, wv = tid >> 6;
  const int wr = wv >> 2, wc = wv & 3;
  const int g16 = lane >> 4, fr = lane & 15;

  const unsigned short* Ag = Y + (size_t)b * NT * NEI + (size_t)(bm * 256) * NEI;
  const unsigned short* Bg = Wt + (size_t)(bn * 256) * NEI;

  __shared__ __align__(16) unsigned short lds[65536];

  f32x4 acc[8][4];
#pragma unroll
  for (int m = 0; m < 8; ++m)
#pragma unroll
    for (int n = 0; n < 4; ++n) acc[m][n] = (f32x4)0.f;

  gemm8_core<NEI / 64>(Ag, Bg, NEI, NEI, lds, acc);

  const int t0 = bm * 256 + wr * 128;
  const int o0 = bn * 256 + wc * 64;
  float bv[4];
#pragma unroll
  for (int n = 0; n < 4; ++n) bv[n] = bias[o0 + n * 16 + fr];
#pragma unroll
  for (int ii = 0; ii < 8; ++ii) {
#pragma unroll
    for (int j = 0; j < 4; ++j) {
      const int t = t0 + (ii >> 2) * 64 + (ii & 3) * 16 + g16 * 4 + j;
      const float sv = S[b * NT + t];
      float* op = out + ((size_t)b * NT + t) * NO + o0;
#pragma unroll
      for (int n = 0; n < 4; ++n) op[n * 16 + fr] = acc[ii][n][j] + bv[n] * sv;
    }
  }
}

// ===========================================================================
// FALLBACK (round-4 verified) — used when ws_size < ~185 MB
// ===========================================================================
__global__ __launch_bounds__(256, 2) void k_gemm1(
    const float* __restrict__ x, const float* __restrict__ W,
    const float* __restrict__ bias, unsigned short* __restrict__ eoT) {
  const int tile = blockIdx.x;
  const int e = blockIdx.y, b = blockIdx.z;
  const int bm = tile >> 2, bn = tile & 3;
  const int tid = threadIdx.x, lane = tid & 63, wv = tid >> 6;
  const int wr = wv >> 1, wc = wv & 1;

  const float* Ag = W + (size_t)e * NO * NI + (size_t)(bm * 128) * NI;
  const float* Bg = x + ((size_t)b * NE + e) * NC * NI + (size_t)(bn * 128) * NI;

  __shared__ __align__(16) unsigned short As[128 * 32];
  __shared__ __align__(16) unsigned short Bs[128 * 32];

  f32x4 acc[4][4];
#pragma unroll
  for (int m = 0; m < 4; ++m)
#pragma unroll
    for (int n = 0; n < 4; ++n) acc[m][n] = (f32x4)0.f;

  for (int k0 = 0; k0 < NI; k0 += 32) {
    __syncthreads();
#pragma unroll
    for (int s = 0; s < 2; ++s) {
      const int q = tid + s * 256;
      const int row = q >> 2, kc = (q & 3) * 8;
      const float* ga = Ag + (size_t)row * NI + k0 + kc;
      float4 a0 = *(const float4*)ga;
      float4 a1 = *(const float4*)(ga + 4);
      *(ushort8*)((char*)As + lds_byte(row, kc * 2)) = cvt8(a0, a1);
      const float* gb = Bg + (size_t)row * NI + k0 + kc;
      float4 b0 = *(const float4*)gb;
      float4 b1 = *(const float4*)(gb + 4);
      *(ushort8*)((char*)Bs + lds_byte(row, kc * 2)) = cvt8(b0, b1);
    }
    __syncthreads();

    const int kb = (lane >> 4) * 16;
    short8 af[4], bfv[4];
#pragma unroll
    for (int m = 0; m < 4; ++m) {
      const int r = wr * 64 + m * 16 + (lane & 15);
      af[m] = *(const short8*)((const char*)As + lds_byte(r, kb));
    }
#pragma unroll
    for (int n = 0; n < 4; ++n) {
      const int r = wc * 64 + n * 16 + (lane & 15);
      bfv[n] = *(const short8*)((const char*)Bs + lds_byte(r, kb));
    }
#pragma unroll
    for (int m = 0; m < 4; ++m)
#pragma unroll
      for (int n = 0; n < 4; ++n)
        acc[m][n] = __builtin_amdgcn_mfma_f32_16x16x32_bf16(
            af[m], bfv[n], acc[m][n], 0, 0, 0);
  }

  const int o0 = bm * 128 + wr * 64;
  const int c0 = bn * 128 + wc * 64;
#pragma unroll
  for (int m = 0; m < 4; ++m) {
#pragma unroll
    for (int j = 0; j < 4; ++j) {
      const int o = o0 + m * 16 + (lane >> 4) * 4 + j;
      const float bvv = bias[o];
      const size_t base = (((size_t)b * NO + o) * NE + e) * NC + c0;
#pragma unroll
      for (int n = 0; n < 4; ++n)
        eoT[base + n * 16 + (lane & 15)] = f2bf(acc[m][n][j] + bvv);
    }
  }
}

__global__ __launch_bounds__(256, 2) void k_gemm2(
    const float* __restrict__ comb, const unsigned short* __restrict__ eoT,
    float* __restrict__ out) {
  const int b = blockIdx.y;
  const int bm = blockIdx.x >> 5;
  const int bn = blockIdx.x & 31;
  const int tid = threadIdx.x, lane = tid & 63, wv = tid >> 6;
  const int wr = wv >> 1, wc = wv & 1;

  const float* Ag = comb + (size_t)b * NT * NEC + (size_t)(bm * 128) * NEC;
  const unsigned short* Bg = eoT + (size_t)b * NO * NEC + (size_t)(bn * 128) * NEC;

  __shared__ __align__(16) unsigned short As[128 * 32];
  __shared__ __align__(16) unsigned short Bs[128 * 32];

  f32x4 acc[4][4];
#pragma unroll
  for (int m = 0; m < 4; ++m)
#pragma unroll
    for (int n = 0; n < 4; ++n) acc[m][n] = (f32x4)0.f;

  for (int k0 = 0; k0 < NEC; k0 += 32) {
    __syncthreads();
#pragma unroll
    for (int s = 0; s < 2; ++s) {
      const int q = tid + s * 256;
      const int row = q >> 2, kc = (q & 3) * 8;
      const float* ga = Ag + (size_t)row * NEC + k0 + kc;
      float4 a0 = *(const float4*)ga;
      float4 a1 = *(const float4*)(ga + 4);
      *(ushort8*)((char*)As + lds_byte(row, kc * 2)) = cvt8(a0, a1);
      ushort8 bvv = *(const ushort8*)(Bg + (size_t)row * NEC + k0 + kc);
      *(ushort8*)((char*)Bs + lds_byte(row, kc * 2)) = bvv;
    }
    __syncthreads();

    const int kb = (lane >> 4) * 16;
    short8 af[4], bfv[4];
#pragma unroll
    for (int m = 0; m < 4; ++m) {
      const int r = wr * 64 + m * 16 + (lane & 15);
      af[m] = *(const short8*)((const char*)As + lds_byte(r, kb));
    }
#pragma unroll
    for (int n = 0; n < 4; ++n) {
      const int r = wc * 64 + n * 16 + (lane & 15);
      bfv[n] = *(const short8*)((const char*)Bs + lds_byte(r, kb));
    }
#pragma unroll
    for (int m = 0; m < 4; ++m)
#pragma unroll
      for (int n = 0; n < 4; ++n)
        acc[m][n] = __builtin_amdgcn_mfma_f32_16x16x32_bf16(
            af[m], bfv[n], acc[m][n], 0, 0, 0);
  }

  const int t0 = bm * 128 + wr * 64;
  const int o0 = bn * 128 + wc * 64;
#pragma unroll
  for (int m = 0; m < 4; ++m) {
#pragma unroll
    for (int j = 0; j < 4; ++j) {
      const int t = t0 + m * 16 + (lane >> 4) * 4 + j;
      float* op = out + ((size_t)b * NT + t) * NO + o0;
#pragma unroll
      for (int n = 0; n < 4; ++n) op[n * 16 + (lane & 15)] = acc[m][n][j];
    }
  }
}

extern "C" void kernel_launch(void* const* d_in, const int* in_sizes, int n_in,
                              void* d_out, int out_size, void* d_ws, size_t ws_size,
                              hipStream_t stream) {
  const float* x    = (const float*)d_in[0];  // [B,E,C,I]
  const float* comb = (const float*)d_in[1];  // [B,T,E,C]
  const float* W    = (const float*)d_in[2];  // [E,O,I]
  const float* bias = (const float*)d_in[3];  // [O]
  float* out = (float*)d_out;                 // [B,T,O]

  // Restructured workspace: Y | cbp | xT | Wt | S
  const size_t Y_ELEMS  = (size_t)NB * NT * NEI;  // 33,554,432
  const size_t C_ELEMS  = (size_t)NB * NT * NEC;  // 33,554,432
  const size_t XT_ELEMS = (size_t)NB * NE * NI * NC;  // 8,388,608
  const size_t WT_ELEMS = (size_t)NO * NE * NI;   // 16,777,216
  const size_t need =
      (Y_ELEMS + C_ELEMS + XT_ELEMS + WT_ELEMS) * 2 + (size_t)NB * NT * 4;

  if (ws_size >= need) {
    unsigned short* Yp  = (unsigned short*)d_ws;
    unsigned short* cbp = Yp + Y_ELEMS;
    unsigned short* xT  = cbp + C_ELEMS;
    unsigned short* Wt  = xT + XT_ELEMS;
    float* S = (float*)(Wt + WT_ELEMS);

    k_cvtT_x<<<2048, 256, 0, stream>>>(x, xT);
    k_cvt_comb<<<NB * NT, 256, 0, stream>>>(comb, cbp, S);
    k_gemm1q<<<512, 512, 0, stream>>>(cbp, xT, Yp);
    k_cvtT_W<<<2048, 256, 0, stream>>>(W, Wt);
    k_gemm2q<<<512, 512, 0, stream>>>(Yp, Wt, bias, S, out);
  } else {
    // Fallback: round-4 verified reg-staged kernels (needs only 134MB)
    unsigned short* eoT = (unsigned short*)d_ws;
    k_gemm1<<<dim3(128, NE, NB), 256, 0, stream>>>(x, W, bias, eoT);
    k_gemm2<<<dim3(512, NB), 256, 0, stream>>>(comb, eoT, out);
  }
}